// Round 3
// baseline (394.214 us; speedup 1.0000x reference)
//
#include <hip/hip_runtime.h>

#define Bq   32
#define Lq   4096
#define Eq   1024
#define OUTq 64
#define NW   16   // waves per gemm-role block
#define TG   8    // rows per group

typedef decltype(__builtin_amdgcn_cvt_pkrtz(0.f, 0.f)) h2;  // 2 x f16

#if defined(__has_builtin)
#if __has_builtin(__builtin_amdgcn_fdot2)
#define HAVE_FDOT2 1
#endif
#endif

static __device__ __forceinline__ float dot2f(unsigned a, h2 b, float c) {
    h2 ah = __builtin_bit_cast(h2, a);
#ifdef HAVE_FDOT2
    return __builtin_amdgcn_fdot2(ah, b, c, false);
#else
    return c + (float)ah[0] * (float)b[0] + (float)ah[1] * (float)b[1];
#endif
}

#define LGKM_BARRIER() asm volatile("s_waitcnt lgkmcnt(0)\n\ts_barrier" ::: "memory")

// ---------------------------------------------------------------------------
// K1: vec[b][e] = inputA[b].W1a[e] + b1a[e] + inputB[b].W1b[e] + b1b[e]
// Wave per e; W rows in registers, loop over b (inputs L2-resident).
// ---------------------------------------------------------------------------
__global__ __launch_bounds__(256) void vec_kernel(
    const float* __restrict__ inA, const float* __restrict__ inB,
    const float* __restrict__ W1a, const float* __restrict__ b1a,
    const float* __restrict__ W1b, const float* __restrict__ b1b,
    float* __restrict__ vec)
{
    int e    = (blockIdx.x * 256 + threadIdx.x) >> 6;
    int lane = threadIdx.x & 63;
    if (e >= Eq) return;

    const float4* wa4 = (const float4*)(W1a + (size_t)e * Eq);
    const float4* wb4 = (const float4*)(W1b + (size_t)e * Eq);
    float4 wa[4], wb[4];
#pragma unroll
    for (int j = 0; j < 4; ++j) { wa[j] = wa4[lane + 64 * j]; wb[j] = wb4[lane + 64 * j]; }
    float bias = b1a[e] + b1b[e];

#pragma unroll 4
    for (int b = 0; b < Bq; ++b) {
        const float4* a4  = (const float4*)(inA + (size_t)b * Eq);
        const float4* bb4 = (const float4*)(inB + (size_t)b * Eq);
        float acc = 0.f;
#pragma unroll
        for (int j = 0; j < 4; ++j) {
            float4 a = a4[lane + 64 * j];
            acc += wa[j].x * a.x + wa[j].y * a.y + wa[j].z * a.z + wa[j].w * a.w;
            float4 v = bb4[lane + 64 * j];
            acc += wb[j].x * v.x + wb[j].y * v.y + wb[j].z * v.z + wb[j].w * v.w;
        }
#pragma unroll
        for (int s = 32; s; s >>= 1) acc += __shfl_xor(acc, s, 64);
        if (lane == 0) vec[(size_t)b * Eq + e] = acc + bias;
    }
}

// ---------------------------------------------------------------------------
// K2: mega kernel, 512 blocks x 1024 threads, two roles:
//   blocks [0,256):   GEMM role — rows t in [0, cache_len]: copy row f32 to
//                     ncache + out = row.W2^T + b2 (f16 dot2, W2 in 32 VGPRs)
//   blocks [256,512): copy role — rows t in (cache_len, L): pure f32 stream
// VGPR<=64 (launch_bounds 1024,8) => 1 gemm + 1 copy block co-resident per
// CU (8 waves/SIMD): copy traffic fills every HBM bubble of the gemm phases.
// ---------------------------------------------------------------------------
__global__ __launch_bounds__(1024, 8) void mega_kernel(
    const float* __restrict__ cache, const float* __restrict__ vec,
    const float* __restrict__ W2, const float* __restrict__ b2,
    float* __restrict__ outp, float* __restrict__ ncache, int cache_len)
{
    __shared__ unsigned rowbuf[TG][Eq / 2];   // f16 pairs, 16 KB
    __shared__ float    part[NW][TG * 64];    // 32 KB

    const int tid = threadIdx.x;

    if (blockIdx.x < 256) {
        // ------------------------- GEMM role -------------------------
        const int rows_out = cache_len + 1;              // 2049
        const int ngg  = (rows_out + TG - 1) / TG;       // 257
        const int b    = blockIdx.x >> 3;
        const int slot = blockIdx.x & 7;
        const int w = tid >> 6, lane = tid & 63;
        const int rsub = tid >> 7, c = tid & 127;

        // W2 f16 slice: lane (=o) holds W2[o][64w .. 64w+63] as 32 h2 regs
        h2 w2h[32];
        const float4* w2p = (const float4*)(W2 + (size_t)lane * Eq + 64 * w);
#pragma unroll
        for (int j = 0; j < 16; ++j) {
            float4 f = w2p[j];
            w2h[2 * j]     = __builtin_amdgcn_cvt_pkrtz(f.x, f.y);
            w2h[2 * j + 1] = __builtin_amdgcn_cvt_pkrtz(f.z, f.w);
        }
        const float bias = b2[lane];

        const float* cb = cache  + (size_t)b * Lq * Eq;
        float*       nb = ncache + (size_t)b * Lq * Eq;
        const float* vb = vec    + (size_t)b * Eq;
        float*       ob = outp   + (size_t)b * rows_out * OUTq;

        float4 gld0, gld1;
        auto fetch = [&](int g) {
            int t = TG * g + rsub;
            if (g < ngg && t <= cache_len) {
                const float* src = (t == cache_len) ? vb : (cb + (size_t)t * Eq);
                gld0 = *(const float4*)(src + 4 * c);
                gld1 = *(const float4*)(src + 4 * c + 512);
            }
        };
        fetch(slot);

        for (int g = slot; g < ngg; g += 8) {
            // phase 1: f32 copy-store + f16 LDS stage + prefetch next group
            int t = TG * g + rsub;
            if (t <= cache_len) {
                float* dst = nb + (size_t)t * Eq;
                *(float4*)(dst + 4 * c)       = gld0;
                *(float4*)(dst + 4 * c + 512) = gld1;
                unsigned u0 = __builtin_bit_cast(unsigned, __builtin_amdgcn_cvt_pkrtz(gld0.x, gld0.y));
                unsigned u1 = __builtin_bit_cast(unsigned, __builtin_amdgcn_cvt_pkrtz(gld0.z, gld0.w));
                unsigned u2 = __builtin_bit_cast(unsigned, __builtin_amdgcn_cvt_pkrtz(gld1.x, gld1.y));
                unsigned u3 = __builtin_bit_cast(unsigned, __builtin_amdgcn_cvt_pkrtz(gld1.z, gld1.w));
                *(uint2*)(&rowbuf[rsub][2 * c])       = make_uint2(u0, u1);
                *(uint2*)(&rowbuf[rsub][2 * c + 256]) = make_uint2(u2, u3);
            }
            fetch(g + 8);

            LGKM_BARRIER();   // A: rowbuf ready; global ops stay in flight

            // phase 2: per-wave K-slice (64 values = 32 h2) via broadcast reads
#pragma unroll
            for (int r = 0; r < TG; ++r) {
                float acc = 0.f;
                const uint4* rp = (const uint4*)(&rowbuf[r][32 * w]);
#pragma unroll
                for (int j = 0; j < 8; ++j) {
                    uint4 v = rp[j];
                    acc = dot2f(v.x, w2h[4 * j],     acc);
                    acc = dot2f(v.y, w2h[4 * j + 1], acc);
                    acc = dot2f(v.z, w2h[4 * j + 2], acc);
                    acc = dot2f(v.w, w2h[4 * j + 3], acc);
                }
                part[w][r * 64 + lane] = acc;
            }

            LGKM_BARRIER();   // B: partials ready

            // phase 3: cross-wave reduce + out store (no barrier C needed:
            // next iter's barrier A orders part reads before next writes)
            if (tid < TG * 64) {
                int rr = tid >> 6;
                int trow = TG * g + rr;
                if (trow < rows_out) {
                    float s = 0.f;
#pragma unroll
                    for (int ww = 0; ww < NW; ++ww) s += part[ww][tid];
                    ob[(size_t)trow * OUTq + lane] = s + bias;
                }
            }
        }
    } else {
        // ------------------------- copy role -------------------------
        const int cb2  = blockIdx.x - 256;          // 0..255
        const int first = cache_len + 1;            // 2049
        const int span  = Lq - first;               // 2047
        const int nrows = Bq * span;                // 65504
        const int rloc  = tid >> 6;                 // 0..15 (wave per row)
        const int lane  = tid & 63;

        const float4* s4 = (const float4*)cache;
        float4*       d4 = (float4*)ncache;

        int Rcur = cb2 * 16 + rloc;
        size_t offc = 0;
        float4 p0, p1, p2, p3;
        if (Rcur < nrows) {
            int bb = Rcur / span, tr = first + Rcur - bb * span;
            offc = ((size_t)bb * Lq + tr) * (Eq / 4) + lane;
            p0 = s4[offc]; p1 = s4[offc + 64]; p2 = s4[offc + 128]; p3 = s4[offc + 192];
        }
#pragma unroll 4
        for (int i = 0; i < 16; ++i) {
            int Rnext = Rcur + 4096;
            size_t offn = 0;
            float4 n0, n1, n2, n3;
            if (Rnext < nrows) {            // issue next loads first
                int bb = Rnext / span, tr = first + Rnext - bb * span;
                offn = ((size_t)bb * Lq + tr) * (Eq / 4) + lane;
                n0 = s4[offn]; n1 = s4[offn + 64]; n2 = s4[offn + 128]; n3 = s4[offn + 192];
            }
            if (Rcur < nrows) {             // store current
                d4[offc] = p0; d4[offc + 64] = p1; d4[offc + 128] = p2; d4[offc + 192] = p3;
            }
            Rcur = Rnext; offc = offn;
            p0 = n0; p1 = n1; p2 = n2; p3 = n3;
        }
    }
}

// ---------------------------------------------------------------------------
extern "C" void kernel_launch(void* const* d_in, const int* in_sizes, int n_in,
                              void* d_out, int out_size, void* d_ws, size_t ws_size,
                              hipStream_t stream)
{
    const float* inA   = (const float*)d_in[0];
    const float* inB   = (const float*)d_in[1];
    const float* cache = (const float*)d_in[2];
    const float* W1a   = (const float*)d_in[3];
    const float* b1a   = (const float*)d_in[4];
    const float* W1b   = (const float*)d_in[5];
    const float* b1b   = (const float*)d_in[6];
    const float* W2    = (const float*)d_in[7];
    const float* b2v   = (const float*)d_in[8];

    float* outp = (float*)d_out;
    int rows_out  = (out_size - Bq * Lq * Eq) / (Bq * OUTq);  // cache_len + 1
    int cache_len = rows_out - 1;                             // 2048
    float* ncache = outp + (size_t)Bq * rows_out * OUTq;
    float* vecbuf = (float*)d_ws;                             // 32*1024 f32

    vec_kernel<<<dim3(256), dim3(256), 0, stream>>>(inA, inB, W1a, b1a, W1b, b1b, vecbuf);

    mega_kernel<<<dim3(512), dim3(1024), 0, stream>>>(cache, vecbuf, W2, b2v,
                                                      outp, ncache, cache_len);
}